// Round 1
// baseline (479.618 us; speedup 1.0000x reference)
//
#include <hip/hip_runtime.h>
#include <hip/hip_bf16.h>

typedef __attribute__((ext_vector_type(4))) float f32x4;
typedef __attribute__((ext_vector_type(8))) short bf8;

#define B_ 2
#define ST 2048
#define SC 1024
#define SK 3072
#define NH 16
#define DH 128
#define KVB 32
#define NT (SK / KVB)     // 96 tiles
#define TGT (ST / KVB)    // 64 target tiles
#define SCALE 0.088388347648318447f

__device__ __forceinline__ unsigned short f2bf(float f) {
    unsigned int u = __float_as_uint(f);
    u += 0x7fffu + ((u >> 16) & 1u);   // round-to-nearest-even
    return (unsigned short)(u >> 16);
}

__global__ __launch_bounds__(256)
void attn_fwd(const float* __restrict__ Q,
              const float* __restrict__ TK,
              const float* __restrict__ TV,
              const float* __restrict__ CK,
              const float* __restrict__ CV,
              const float* __restrict__ BP,
              float* __restrict__ OUT)
{
    // K tile: [32][128] bf16, XOR-swizzled (byte ^= (row&7)<<4)
    // V tile: transposed [d=128][kk stride 40] bf16, XOR-swizzled on d
    // P tile: per-wave [16][stride 56] bf16 (C/D-layout -> A-layout round trip)
    __shared__ __align__(16) unsigned short Ks[2][KVB * DH];
    __shared__ __align__(16) unsigned short Vt[2][DH * 40];
    __shared__ __align__(16) unsigned short Ps[4][16 * 56];

    const int tid = threadIdx.x;
    const int w   = tid >> 6;
    const int l   = tid & 63;
    const int l15 = l & 15;
    const int g   = l >> 4;

    const int qt = blockIdx.x;        // 0..31 q-tile
    const int bh = blockIdx.y;        // 0..31 = b*16+h
    const int bb = bh >> 4;
    const int hh = bh & 15;

    const float bias_c = BP[0];

    // ---- Q fragments (A-layout): lane holds Q[row=l15][kc*32 + g*8 + j] ----
    const int qrow = qt * 64 + w * 16 + l15;
    const float* qp = Q + (((size_t)bb * ST + qrow) * NH + hh) * DH;
    bf8 qf[4];
#pragma unroll
    for (int kc = 0; kc < 4; ++kc) {
        const f32x4 x0 = *(const f32x4*)(qp + kc * 32 + g * 8);
        const f32x4 x1 = *(const f32x4*)(qp + kc * 32 + g * 8 + 4);
        bf8 v;
        v[0]=(short)f2bf(x0[0]); v[1]=(short)f2bf(x0[1]);
        v[2]=(short)f2bf(x0[2]); v[3]=(short)f2bf(x0[3]);
        v[4]=(short)f2bf(x1[0]); v[5]=(short)f2bf(x1[1]);
        v[6]=(short)f2bf(x1[2]); v[7]=(short)f2bf(x1[3]);
        qf[kc] = v;
    }

    f32x4 oa[8];
#pragma unroll
    for (int i = 0; i < 8; ++i) oa[i] = (f32x4){0.f, 0.f, 0.f, 0.f};
    float mrow[4] = {-1e30f, -1e30f, -1e30f, -1e30f};
    float lrow[4] = {0.f, 0.f, 0.f, 0.f};

    auto stage = [&](int t, int buf) {
        const int kv0 = t * KVB;
#pragma unroll
        for (int i = 0; i < 2; ++i) {
            const int c    = tid + (i << 8);   // 0..511 chunk id
            const int row  = c >> 4;           // 0..31
            const int colb = (c & 15) << 3;    // 0,8,...,120
            const int kk   = kv0 + row;
            const float *kp, *vp;
            if (kk < ST) {
                const size_t off = (((size_t)bb * ST + kk) * NH + hh) * DH;
                kp = TK + off; vp = TV + off;
            } else {
                const size_t off = (((size_t)bb * SC + (kk - ST)) * NH + hh) * DH;
                kp = CK + off; vp = CV + off;
            }
            const f32x4 k0 = *(const f32x4*)(kp + colb);
            const f32x4 k1 = *(const f32x4*)(kp + colb + 4);
            const f32x4 v0 = *(const f32x4*)(vp + colb);
            const f32x4 v1 = *(const f32x4*)(vp + colb + 4);
            bf8 kv;
            kv[0]=(short)f2bf(k0[0]); kv[1]=(short)f2bf(k0[1]);
            kv[2]=(short)f2bf(k0[2]); kv[3]=(short)f2bf(k0[3]);
            kv[4]=(short)f2bf(k1[0]); kv[5]=(short)f2bf(k1[1]);
            kv[6]=(short)f2bf(k1[2]); kv[7]=(short)f2bf(k1[3]);
            int ko = row * 256 + (colb << 1);
            ko ^= (row & 7) << 4;
            *(bf8*)((char*)Ks[buf] + ko) = kv;
#pragma unroll
            for (int j = 0; j < 8; ++j) {
                const float vj = (j < 4) ? v0[j] : v1[j - 4];
                const int d = colb + j;
                int vo = d * 80 + row * 2;
                vo ^= ((d >> 3) & 7) << 4;
                *(unsigned short*)((char*)Vt[buf] + vo) = f2bf(vj);
            }
        }
    };

    stage(0, 0);

    for (int t = 0; t < NT; ++t) {
        __syncthreads();
        if (t + 1 < NT) stage(t + 1, (t + 1) & 1);
        const int buf = t & 1;
        const float bias = (t >= TGT) ? bias_c : 0.f;

        // ---- QK^T: S[16 q rows][32 kv cols], two 16-col n-tiles ----
        f32x4 s0 = {0.f,0.f,0.f,0.f}, s1 = {0.f,0.f,0.f,0.f};
#pragma unroll
        for (int kc = 0; kc < 4; ++kc) {
            const int cb = (kc * 32 + g * 8) * 2;
            int o0 = l15 * 256 + cb;        o0 ^= (l15 & 7) << 4;
            const bf8 kf0 = *(const bf8*)((const char*)Ks[buf] + o0);
            s0 = __builtin_amdgcn_mfma_f32_16x16x32_bf16(qf[kc], kf0, s0, 0, 0, 0);
            const int r1 = 16 + l15;
            int o1 = r1 * 256 + cb;         o1 ^= (r1 & 7) << 4;
            const bf8 kf1 = *(const bf8*)((const char*)Ks[buf] + o1);
            s1 = __builtin_amdgcn_mfma_f32_16x16x32_bf16(qf[kc], kf1, s1, 0, 0, 0);
        }

        // ---- online softmax (wave-parallel; row = g*4+r, cols across 16 lanes) ----
#pragma unroll
        for (int r = 0; r < 4; ++r) {
            const float v0 = s0[r] * SCALE + bias;
            const float v1 = s1[r] * SCALE + bias;
            float mx = fmaxf(v0, v1);
            mx = fmaxf(mx, __shfl_xor(mx, 1));
            mx = fmaxf(mx, __shfl_xor(mx, 2));
            mx = fmaxf(mx, __shfl_xor(mx, 4));
            mx = fmaxf(mx, __shfl_xor(mx, 8));
            const float mnew = fmaxf(mrow[r], mx);
            const float corr = __expf(mrow[r] - mnew);
            mrow[r] = mnew;
            const float p0 = __expf(v0 - mnew);
            const float p1 = __expf(v1 - mnew);
            float rs = p0 + p1;
            rs += __shfl_xor(rs, 1);
            rs += __shfl_xor(rs, 2);
            rs += __shfl_xor(rs, 4);
            rs += __shfl_xor(rs, 8);
            lrow[r] = lrow[r] * corr + rs;
#pragma unroll
            for (int dc = 0; dc < 8; ++dc) oa[dc][r] *= corr;
            const int prow = g * 4 + r;
            Ps[w][prow * 56 + l15]      = f2bf(p0);
            Ps[w][prow * 56 + 16 + l15] = f2bf(p1);
        }

        // ---- PV: O[16 q][128 d] += P[16][32] * V[32][128] ----
        const bf8 pf = *(const bf8*)&Ps[w][l15 * 56 + g * 8];
#pragma unroll
        for (int dc = 0; dc < 8; ++dc) {
            const int d = dc * 16 + l15;
            int vo = d * 80 + g * 16;
            vo ^= ((d >> 3) & 7) << 4;
            const bf8 vf = *(const bf8*)((const char*)Vt[buf] + vo);
            oa[dc] = __builtin_amdgcn_mfma_f32_16x16x32_bf16(pf, vf, oa[dc], 0, 0, 0);
        }
    }

    // ---- epilogue: normalize and store fp32 ----
    float* op = OUT + (((size_t)bb * ST + qt * 64 + w * 16) * NH + hh) * DH;
#pragma unroll
    for (int r = 0; r < 4; ++r) {
        const float inv = 1.0f / lrow[r];
        float* rp = op + (size_t)(g * 4 + r) * (NH * DH);
#pragma unroll
        for (int dc = 0; dc < 8; ++dc)
            rp[dc * 16 + l15] = oa[dc][r] * inv;
    }
}

extern "C" void kernel_launch(void* const* d_in, const int* in_sizes, int n_in,
                              void* d_out, int out_size, void* d_ws, size_t ws_size,
                              hipStream_t stream) {
    const float* q  = (const float*)d_in[0];
    const float* tk = (const float*)d_in[1];
    const float* tv = (const float*)d_in[2];
    const float* ck = (const float*)d_in[3];
    const float* cv = (const float*)d_in[4];
    const float* bp = (const float*)d_in[5];
    float* out = (float*)d_out;
    dim3 grid(ST / 64, B_ * NH);
    attn_fwd<<<grid, 256, 0, stream>>>(q, tk, tv, ck, cv, bp, out);
}

// Round 2
// 357.169 us; speedup vs baseline: 1.3428x; 1.3428x over previous
//
#include <hip/hip_runtime.h>
#include <hip/hip_bf16.h>

typedef __attribute__((ext_vector_type(4))) float f32x4;
typedef __attribute__((ext_vector_type(8))) short bf8;
typedef __attribute__((ext_vector_type(2))) int i32x2;

#define B_ 2
#define ST 2048
#define SC 1024
#define SK 3072
#define NH 16
#define DH 128
#define KVB 64
#define NT (SK / KVB)     // 48 tiles
#define TGT (ST / KVB)    // 32 target tiles
#define SCALE 0.088388347648318447f

__device__ __forceinline__ unsigned short f2bf(float f) {
    union { __hip_bfloat16 b; unsigned short u; } c;
    c.b = __float2bfloat16(f);
    return c.u;
}

__device__ __forceinline__ i32x2 tr_read(unsigned a) {
    i32x2 d;
    asm volatile("ds_read_b64_tr_b16 %0, %1" : "=v"(d) : "v"(a));
    return d;
}

__device__ __forceinline__ bf8 mk_bf8(i32x2 a, i32x2 b) {
    union { i32x2 h[2]; bf8 v; } u;
    u.h[0] = a; u.h[1] = b;
    return u.v;
}

__global__ __launch_bounds__(256, 2)
void attn_fwd(const float* __restrict__ Q,
              const float* __restrict__ TK,
              const float* __restrict__ TV,
              const float* __restrict__ CK,
              const float* __restrict__ CV,
              const float* __restrict__ BP,
              float* __restrict__ OUT)
{
    // K: row-major [64][128] bf16, XOR-swizzled (byte ^= (row&7)<<4)
    // V: subtiled [kb=k/4][dc=d/16][4][16] bf16 (tiles 128 B) for ds_read_b64_tr_b16
    // Pt: per-wave P transposed [kv=64][q=16] bf16 (rows 32 B; 4-row tiles = 128 B)
    __shared__ __align__(16) unsigned short Ks[2][KVB * DH];
    __shared__ __align__(16) unsigned short Vs[2][KVB * DH];
    __shared__ __align__(16) unsigned short Pt[4][KVB * 16];

    const int tid = threadIdx.x;
    const int w   = tid >> 6;
    const int l   = tid & 63;
    const int l15 = l & 15;
    const int g   = l >> 4;

    const int qt = blockIdx.x;        // 0..31 q-tile (64 rows)
    const int bh = blockIdx.y;        // 0..31 = b*16+h
    const int bb = bh >> 4;
    const int hh = bh & 15;

    const float bias_c = BP[0];

    // ---- Q fragments (A-layout), pre-scaled by softmax scale ----
    const int qrow = qt * 64 + w * 16 + l15;
    const float* qp = Q + (((size_t)bb * ST + qrow) * NH + hh) * DH;
    bf8 qf[4];
#pragma unroll
    for (int kc = 0; kc < 4; ++kc) {
        const f32x4 x0 = *(const f32x4*)(qp + kc * 32 + g * 8);
        const f32x4 x1 = *(const f32x4*)(qp + kc * 32 + g * 8 + 4);
        bf8 v;
        v[0]=(short)f2bf(x0[0]*SCALE); v[1]=(short)f2bf(x0[1]*SCALE);
        v[2]=(short)f2bf(x0[2]*SCALE); v[3]=(short)f2bf(x0[3]*SCALE);
        v[4]=(short)f2bf(x1[0]*SCALE); v[5]=(short)f2bf(x1[1]*SCALE);
        v[6]=(short)f2bf(x1[2]*SCALE); v[7]=(short)f2bf(x1[3]*SCALE);
        qf[kc] = v;
    }

    f32x4 oa[8];
#pragma unroll
    for (int i = 0; i < 8; ++i) oa[i] = (f32x4){0.f, 0.f, 0.f, 0.f};
    float mrow[4] = {-1e30f, -1e30f, -1e30f, -1e30f};
    float lrow[4] = {0.f, 0.f, 0.f, 0.f};

    // LDS raw addresses for tr-reads
    const unsigned vsBase = (unsigned)(size_t)&Vs[0][0];
    const unsigned ptBase = (unsigned)(size_t)&Pt[0][0];
    const unsigned vA0 = vsBase + (unsigned)(g * 2048 + l15 * 8);
    const unsigned pA  = ptBase + (unsigned)(w * 2048 + g * 256 + l15 * 8);

    auto stage = [&](int t, int buf) {
        const int kv0 = t * KVB;
#pragma unroll
        for (int i = 0; i < 4; ++i) {
            const int c    = tid + (i << 8);   // 0..1023 chunk id
            const int row  = c >> 4;           // 0..63
            const int colb = (c & 15) << 3;    // 0,8,...,120
            const int kk   = kv0 + row;
            const float *kp, *vp;
            if (kk < ST) {
                const size_t off = (((size_t)bb * ST + kk) * NH + hh) * DH;
                kp = TK + off; vp = TV + off;
            } else {
                const size_t off = (((size_t)bb * SC + (kk - ST)) * NH + hh) * DH;
                kp = CK + off; vp = CV + off;
            }
            const f32x4 k0 = *(const f32x4*)(kp + colb);
            const f32x4 k1 = *(const f32x4*)(kp + colb + 4);
            const f32x4 v0 = *(const f32x4*)(vp + colb);
            const f32x4 v1 = *(const f32x4*)(vp + colb + 4);
            bf8 kv, vv;
            kv[0]=(short)f2bf(k0[0]); kv[1]=(short)f2bf(k0[1]);
            kv[2]=(short)f2bf(k0[2]); kv[3]=(short)f2bf(k0[3]);
            kv[4]=(short)f2bf(k1[0]); kv[5]=(short)f2bf(k1[1]);
            kv[6]=(short)f2bf(k1[2]); kv[7]=(short)f2bf(k1[3]);
            vv[0]=(short)f2bf(v0[0]); vv[1]=(short)f2bf(v0[1]);
            vv[2]=(short)f2bf(v0[2]); vv[3]=(short)f2bf(v0[3]);
            vv[4]=(short)f2bf(v1[0]); vv[5]=(short)f2bf(v1[1]);
            vv[6]=(short)f2bf(v1[2]); vv[7]=(short)f2bf(v1[3]);
            int ko = row * 256 + (colb << 1);
            ko ^= (row & 7) << 4;
            *(bf8*)((char*)Ks[buf] + ko) = kv;
            const int vo = ((row >> 2) * 8 + (colb >> 4)) * 128 + (row & 3) * 32 + ((colb & 15) << 1);
            *(bf8*)((char*)Vs[buf] + vo) = vv;
        }
    };

    stage(0, 0);

    for (int t = 0; t < NT; ++t) {
        __syncthreads();
        if (t + 1 < NT) stage(t + 1, (t + 1) & 1);
        const int buf = t & 1;
        const float bias = (t >= TGT) ? bias_c : 0.f;

        // ---- QK^T: S[16 q][64 kv] as four 16-col n-tiles ----
        f32x4 s[4];
#pragma unroll
        for (int nt = 0; nt < 4; ++nt) s[nt] = (f32x4){0.f, 0.f, 0.f, 0.f};
        __builtin_amdgcn_s_setprio(1);
#pragma unroll
        for (int kc = 0; kc < 4; ++kc) {
            const int cb = (kc * 32 + g * 8) * 2;
#pragma unroll
            for (int nt = 0; nt < 4; ++nt) {
                const int r = nt * 16 + l15;
                int o = r * 256 + cb;
                o ^= (r & 7) << 4;
                const bf8 kf = *(const bf8*)((const char*)Ks[buf] + o);
                s[nt] = __builtin_amdgcn_mfma_f32_16x16x32_bf16(qf[kc], kf, s[nt], 0, 0, 0);
            }
        }
        __builtin_amdgcn_s_setprio(0);

        // ---- online softmax (wave-parallel), defer-max THR=8 ----
        float mx4[4];
        bool need = false;
#pragma unroll
        for (int r = 0; r < 4; ++r) {
            const float a0 = s[0][r] + bias, a1 = s[1][r] + bias;
            const float a2 = s[2][r] + bias, a3 = s[3][r] + bias;
            float mx = fmaxf(fmaxf(a0, a1), fmaxf(a2, a3));
            mx = fmaxf(mx, __shfl_xor(mx, 1));
            mx = fmaxf(mx, __shfl_xor(mx, 2));
            mx = fmaxf(mx, __shfl_xor(mx, 4));
            mx = fmaxf(mx, __shfl_xor(mx, 8));
            mx4[r] = mx;
            need = need || (mx > mrow[r] + 8.f);
        }
        if (__any(need)) {
#pragma unroll
            for (int r = 0; r < 4; ++r) {
                const float mnew = fmaxf(mrow[r], mx4[r]);
                const float corr = __expf(mrow[r] - mnew);
                mrow[r] = mnew;
                lrow[r] *= corr;
#pragma unroll
                for (int dc = 0; dc < 8; ++dc) oa[dc][r] *= corr;
            }
        }
        float pp[4][4];   // [nt][r]
#pragma unroll
        for (int r = 0; r < 4; ++r) {
            const float m_ = mrow[r];
            float rs = 0.f;
#pragma unroll
            for (int nt = 0; nt < 4; ++nt) {
                const float p = __expf(s[nt][r] + bias - m_);
                pp[nt][r] = p;
                rs += p;
            }
            rs += __shfl_xor(rs, 1);
            rs += __shfl_xor(rs, 2);
            rs += __shfl_xor(rs, 4);
            rs += __shfl_xor(rs, 8);
            lrow[r] += rs;
        }
        // ---- pack P -> Pt (transposed, [kv][q]): one 8B write per n-tile ----
        char* ptw = (char*)Pt[w] + l15 * 32 + g * 8;
#pragma unroll
        for (int nt = 0; nt < 4; ++nt) {
            const unsigned lo = (unsigned)f2bf(pp[nt][0]) | ((unsigned)f2bf(pp[nt][1]) << 16);
            const unsigned hi = (unsigned)f2bf(pp[nt][2]) | ((unsigned)f2bf(pp[nt][3]) << 16);
            i32x2 d2; d2[0] = (int)lo; d2[1] = (int)hi;
            *(i32x2*)(ptw + nt * 512) = d2;
        }

        // ---- PV via HW transpose reads ----
        asm volatile("" ::: "memory");     // order Pt stores before tr-reads
        const unsigned vA = vA0 + (unsigned)(buf << 14);
        i32x2 pt_[2][2];
        i32x2 vt_[2][8][2];
#pragma unroll
        for (int kr = 0; kr < 2; ++kr) {
            const unsigned pa = pA + kr * 1024;
            pt_[kr][0] = tr_read(pa);
            pt_[kr][1] = tr_read(pa + 128);
            const unsigned vb = vA + kr * 8192;
#pragma unroll
            for (int dc = 0; dc < 8; ++dc) {
                vt_[kr][dc][0] = tr_read(vb + dc * 128);
                vt_[kr][dc][1] = tr_read(vb + dc * 128 + 1024);
            }
        }
        asm volatile("s_waitcnt lgkmcnt(0)");
        __builtin_amdgcn_sched_barrier(0);
        __builtin_amdgcn_s_setprio(1);
#pragma unroll
        for (int kr = 0; kr < 2; ++kr) {
            const bf8 pf = mk_bf8(pt_[kr][0], pt_[kr][1]);
#pragma unroll
            for (int dc = 0; dc < 8; ++dc) {
                const bf8 vf = mk_bf8(vt_[kr][dc][0], vt_[kr][dc][1]);
                oa[dc] = __builtin_amdgcn_mfma_f32_16x16x32_bf16(pf, vf, oa[dc], 0, 0, 0);
            }
        }
        __builtin_amdgcn_s_setprio(0);
    }

    // ---- epilogue: normalize and store fp32 ----
    float* op = OUT + (((size_t)bb * ST + qt * 64 + w * 16) * NH + hh) * DH;
#pragma unroll
    for (int r = 0; r < 4; ++r) {
        const float inv = 1.0f / lrow[r];
        float* rp = op + (size_t)(g * 4 + r) * (NH * DH);
#pragma unroll
        for (int dc = 0; dc < 8; ++dc)
            rp[dc * 16 + l15] = oa[dc][r] * inv;
    }
}

extern "C" void kernel_launch(void* const* d_in, const int* in_sizes, int n_in,
                              void* d_out, int out_size, void* d_ws, size_t ws_size,
                              hipStream_t stream) {
    const float* q  = (const float*)d_in[0];
    const float* tk = (const float*)d_in[1];
    const float* tv = (const float*)d_in[2];
    const float* ck = (const float*)d_in[3];
    const float* cv = (const float*)d_in[4];
    const float* bp = (const float*)d_in[5];
    float* out = (float*)d_out;
    dim3 grid(ST / 64, B_ * NH);
    attn_fwd<<<grid, 256, 0, stream>>>(q, tk, tv, ck, cv, bp, out);
}

// Round 3
// 294.197 us; speedup vs baseline: 1.6303x; 1.2140x over previous
//
#include <hip/hip_runtime.h>
#include <hip/hip_bf16.h>

typedef __attribute__((ext_vector_type(4))) float f32x4;
typedef __attribute__((ext_vector_type(8))) short bf8;
typedef __attribute__((ext_vector_type(2))) int i32x2;

#define B_ 2
#define ST 2048
#define SC 1024
#define SK 3072
#define NH 16
#define DH 128
#define KVB 64
#define NT (SK / KVB)     // 48 tiles
#define TGT (ST / KVB)    // 32 target tiles
#define SCALE 0.088388347648318447f

__device__ __forceinline__ unsigned short f2bf(float f) {
    union { __hip_bfloat16 b; unsigned short u; } c;
    c.b = __float2bfloat16(f);
    return c.u;
}

__device__ __forceinline__ i32x2 tr_read(unsigned a) {
    i32x2 d;
    asm volatile("ds_read_b64_tr_b16 %0, %1" : "=v"(d) : "v"(a));
    return d;
}

__device__ __forceinline__ bf8 mk_bf8(i32x2 a, i32x2 b) {
    union { i32x2 h[2]; bf8 v; } u;
    u.h[0] = a; u.h[1] = b;
    return u.v;
}

__device__ __forceinline__ bf8 pack_bf8(f32x4 a, f32x4 b) {
    bf8 v;
    v[0]=(short)f2bf(a[0]); v[1]=(short)f2bf(a[1]);
    v[2]=(short)f2bf(a[2]); v[3]=(short)f2bf(a[3]);
    v[4]=(short)f2bf(b[0]); v[5]=(short)f2bf(b[1]);
    v[6]=(short)f2bf(b[2]); v[7]=(short)f2bf(b[3]);
    return v;
}

__global__ __launch_bounds__(256, 2)
void attn_fwd(const float* __restrict__ Q,
              const float* __restrict__ TK,
              const float* __restrict__ TV,
              const float* __restrict__ CK,
              const float* __restrict__ CV,
              const float* __restrict__ BP,
              float* __restrict__ OUT)
{
    // K: logical [64][128] bf16 XOR-swizzled (byte ^= (row&7)<<4); stored via
    //    LINEAR ds_write (slot=chunk) with the swizzle folded into the global
    //    source column:  chunk c -> row=c>>4, col8 = ((c&15)^(row&7))*8.
    // V: subtiled [k/4][d/16][4][16] for ds_read_b64_tr_b16; also LINEAR write:
    //    chunk c -> row = (c>>6)*4 + ((c>>1)&3), col8 = ((c>>3)&7)*16 + (c&1)*8.
    // Pt: per-wave P transposed [kv=64][q=16] bf16.
    __shared__ __align__(16) unsigned short Ks[2][KVB * DH];
    __shared__ __align__(16) unsigned short Vs[2][KVB * DH];
    __shared__ __align__(16) unsigned short Pt[4][KVB * 16];

    const int tid = threadIdx.x;
    const int w   = tid >> 6;
    const int l   = tid & 63;
    const int l15 = l & 15;
    const int g   = l >> 4;

    // XCD-aware mapping: 8 XCDs x 4 bh each; the 32 q-tiles of one bh stay on
    // one XCD so its 3.1 MB K/V lives in that XCD's L2.
    const int bid = blockIdx.x;
    const int xcd = bid & 7;
    const int sub = bid >> 3;          // 0..127
    const int bh  = xcd * 4 + (sub >> 5);
    const int qt  = sub & 31;
    const int bb  = bh >> 4;
    const int hh  = bh & 15;

    const float bias_c = BP[0];

    // ---- Q fragments (A-layout), pre-scaled by softmax scale ----
    const int qrow = qt * 64 + w * 16 + l15;
    const float* qp = Q + (((size_t)bb * ST + qrow) * NH + hh) * DH;
    bf8 qf[4];
#pragma unroll
    for (int kc = 0; kc < 4; ++kc) {
        const f32x4 x0 = *(const f32x4*)(qp + kc * 32 + g * 8);
        const f32x4 x1 = *(const f32x4*)(qp + kc * 32 + g * 8 + 4);
        bf8 v;
        v[0]=(short)f2bf(x0[0]*SCALE); v[1]=(short)f2bf(x0[1]*SCALE);
        v[2]=(short)f2bf(x0[2]*SCALE); v[3]=(short)f2bf(x0[3]*SCALE);
        v[4]=(short)f2bf(x1[0]*SCALE); v[5]=(short)f2bf(x1[1]*SCALE);
        v[6]=(short)f2bf(x1[2]*SCALE); v[7]=(short)f2bf(x1[3]*SCALE);
        qf[kc] = v;
    }

    f32x4 oa[8];
#pragma unroll
    for (int i = 0; i < 8; ++i) oa[i] = (f32x4){0.f, 0.f, 0.f, 0.f};
    float mrow[4] = {-1e30f, -1e30f, -1e30f, -1e30f};
    float lrow[4] = {0.f, 0.f, 0.f, 0.f};

    // staging registers (T14 async-STAGE: issue-early / write-late)
    f32x4 skr[4][2], svr[4][2];

    const unsigned vsBase = (unsigned)(size_t)&Vs[0][0];
    const unsigned ptBase = (unsigned)(size_t)&Pt[0][0];
    const unsigned vA0 = vsBase + (unsigned)(g * 2048 + l15 * 8);
    const unsigned pA  = ptBase + (unsigned)(w * 2048 + g * 256 + l15 * 8);

    auto stage_load = [&](int t) {
        const int kv0 = t * KVB;
        const float *kb, *vb;
        if (kv0 < ST) {
            const size_t off = (((size_t)bb * ST + kv0) * NH + hh) * DH;
            kb = TK + off; vb = TV + off;
        } else {
            const size_t off = (((size_t)bb * SC + (kv0 - ST)) * NH + hh) * DH;
            kb = CK + off; vb = CV + off;
        }
#pragma unroll
        for (int i = 0; i < 4; ++i) {
            const int c = tid + (i << 8);          // 0..1023
            const int krow = c >> 4;
            const int kcol = ((c & 15) ^ (krow & 7)) << 3;
            const float* kp = kb + (size_t)krow * (NH * DH) + kcol;
            skr[i][0] = *(const f32x4*)kp;
            skr[i][1] = *(const f32x4*)(kp + 4);
            const int vrow = ((c >> 6) << 2) | ((c >> 1) & 3);
            const int vcol = (((c >> 3) & 7) << 4) | ((c & 1) << 3);
            const float* vp = vb + (size_t)vrow * (NH * DH) + vcol;
            svr[i][0] = *(const f32x4*)vp;
            svr[i][1] = *(const f32x4*)(vp + 4);
        }
    };

    auto stage_write = [&](int buf) {
#pragma unroll
        for (int i = 0; i < 4; ++i) {
            const int c = tid + (i << 8);
            *(bf8*)((char*)Ks[buf] + c * 16) = pack_bf8(skr[i][0], skr[i][1]);
            *(bf8*)((char*)Vs[buf] + c * 16) = pack_bf8(svr[i][0], svr[i][1]);
        }
    };

    stage_load(0);
    stage_write(0);

    for (int t = 0; t < NT; ++t) {
        __syncthreads();                 // buf[t&1] visible; buf[t&1^1] free
        if (t + 1 < NT) stage_load(t + 1);   // issue loads, consume at end
        const int buf = t & 1;
        const float bias = (t >= TGT) ? bias_c : 0.f;

        // ---- QK^T: S[16 q][64 kv] as four 16-col n-tiles ----
        f32x4 s[4];
#pragma unroll
        for (int nt = 0; nt < 4; ++nt) s[nt] = (f32x4){0.f, 0.f, 0.f, 0.f};
        __builtin_amdgcn_s_setprio(1);
#pragma unroll
        for (int kc = 0; kc < 4; ++kc) {
            const int cb = (kc * 32 + g * 8) * 2;
#pragma unroll
            for (int nt = 0; nt < 4; ++nt) {
                const int r = nt * 16 + l15;
                int o = r * 256 + cb;
                o ^= (r & 7) << 4;
                const bf8 kf = *(const bf8*)((const char*)Ks[buf] + o);
                s[nt] = __builtin_amdgcn_mfma_f32_16x16x32_bf16(qf[kc], kf, s[nt], 0, 0, 0);
            }
        }
        __builtin_amdgcn_s_setprio(0);

        // ---- online softmax (wave-parallel), defer-max THR=8 ----
        float mx4[4];
        bool need = false;
#pragma unroll
        for (int r = 0; r < 4; ++r) {
            float mx = fmaxf(fmaxf(s[0][r], s[1][r]), fmaxf(s[2][r], s[3][r]));
            mx = fmaxf(mx, __shfl_xor(mx, 1));
            mx = fmaxf(mx, __shfl_xor(mx, 2));
            mx = fmaxf(mx, __shfl_xor(mx, 4));
            mx = fmaxf(mx, __shfl_xor(mx, 8));
            mx4[r] = mx + bias;
            need = need || (mx4[r] > mrow[r] + 8.f);
        }
        if (__any(need)) {
#pragma unroll
            for (int r = 0; r < 4; ++r) {
                const float mnew = fmaxf(mrow[r], mx4[r]);
                const float corr = __expf(mrow[r] - mnew);
                mrow[r] = mnew;
                lrow[r] *= corr;
#pragma unroll
                for (int dc = 0; dc < 8; ++dc) oa[dc][r] *= corr;
            }
        }
        float pp[4][4];   // [nt][r]
#pragma unroll
        for (int r = 0; r < 4; ++r) {
            const float zb = bias - mrow[r];
            float rs = 0.f;
#pragma unroll
            for (int nt = 0; nt < 4; ++nt) {
                const float p = __expf(s[nt][r] + zb);
                pp[nt][r] = p;
                rs += p;
            }
            rs += __shfl_xor(rs, 1);
            rs += __shfl_xor(rs, 2);
            rs += __shfl_xor(rs, 4);
            rs += __shfl_xor(rs, 8);
            lrow[r] += rs;
        }
        // ---- pack P -> Pt (transposed [kv][q]) ----
        char* ptw = (char*)Pt[w] + l15 * 32 + g * 8;
#pragma unroll
        for (int nt = 0; nt < 4; ++nt) {
            const unsigned lo = (unsigned)f2bf(pp[nt][0]) | ((unsigned)f2bf(pp[nt][1]) << 16);
            const unsigned hi = (unsigned)f2bf(pp[nt][2]) | ((unsigned)f2bf(pp[nt][3]) << 16);
            i32x2 d2; d2[0] = (int)lo; d2[1] = (int)hi;
            *(i32x2*)(ptw + nt * 512) = d2;
        }

        // ---- PV via HW transpose reads, per-kr clusters ----
        asm volatile("" ::: "memory");     // order Pt stores before tr-reads
        const unsigned vA = vA0 + (unsigned)(buf << 14);
#pragma unroll
        for (int kr = 0; kr < 2; ++kr) {
            const unsigned pa = pA + kr * 1024;
            i32x2 p0 = tr_read(pa);
            i32x2 p1 = tr_read(pa + 128);
            const unsigned vb = vA + kr * 8192;
            i32x2 vt_[8][2];
#pragma unroll
            for (int dc = 0; dc < 8; ++dc) {
                vt_[dc][0] = tr_read(vb + dc * 128);
                vt_[dc][1] = tr_read(vb + dc * 128 + 1024);
            }
            asm volatile("s_waitcnt lgkmcnt(0)");
            __builtin_amdgcn_sched_barrier(0);
            __builtin_amdgcn_s_setprio(1);
            const bf8 pf = mk_bf8(p0, p1);
#pragma unroll
            for (int dc = 0; dc < 8; ++dc) {
                const bf8 vf = mk_bf8(vt_[dc][0], vt_[dc][1]);
                oa[dc] = __builtin_amdgcn_mfma_f32_16x16x32_bf16(pf, vf, oa[dc], 0, 0, 0);
            }
            __builtin_amdgcn_s_setprio(0);
        }

        // ---- write-late: next tile's staged regs -> LDS ----
        if (t + 1 < NT) stage_write(buf ^ 1);
    }

    // ---- epilogue: normalize and store fp32 ----
    float* op = OUT + (((size_t)bb * ST + qt * 64 + w * 16) * NH + hh) * DH;
#pragma unroll
    for (int r = 0; r < 4; ++r) {
        const float inv = 1.0f / lrow[r];
        float* rp = op + (size_t)(g * 4 + r) * (NH * DH);
#pragma unroll
        for (int dc = 0; dc < 8; ++dc)
            rp[dc * 16 + l15] = oa[dc][r] * inv;
    }
}

extern "C" void kernel_launch(void* const* d_in, const int* in_sizes, int n_in,
                              void* d_out, int out_size, void* d_ws, size_t ws_size,
                              hipStream_t stream) {
    const float* q  = (const float*)d_in[0];
    const float* tk = (const float*)d_in[1];
    const float* tv = (const float*)d_in[2];
    const float* ck = (const float*)d_in[3];
    const float* cv = (const float*)d_in[4];
    const float* bp = (const float*)d_in[5];
    float* out = (float*)d_out;
    attn_fwd<<<dim3(ST / 64 * B_ * NH), 256, 0, stream>>>(q, tk, tv, ck, cv, bp, out);
}